// Round 1
// baseline (9820.432 us; speedup 1.0000x reference)
//
#include <hip/hip_runtime.h>

// ---------------------------------------------------------------------------
// GRU scan on MI355X. Phase 1: bf16 GEMM P = X W^T + b. Phase 2: persistent
// scan, 2 groups x 32 wgs, U weights in VGPRs.
// R3 change: flag-free TAGGED-PAYLOAD dataflow. h and r*h cross-wg traffic is
// fp32 with generation tag in the mantissa LSB, double-buffered by t&1.
// Consumers poll the payload itself (re-load stale 16B chunks) -> no flags,
// no vmcnt-drain-before-flag, no cross-wg barrier. clear_tags invalidates the
// buffers each run (prevents stale-tag aliasing across bench re-runs).
// ---------------------------------------------------------------------------

typedef __attribute__((ext_vector_type(8))) __bf16 bf16x8;
typedef __attribute__((ext_vector_type(4))) float f32x4;
typedef __attribute__((ext_vector_type(4))) unsigned int u32x4;
typedef unsigned short ushort_t;
typedef unsigned long long u64;

#define DIM_ 1024
#define BATCH_ 32
#define T_ 1024
#define NC_ 3072  // 3*DIM

// workspace layout (bytes)
static constexpr size_t OFF_P     = 0;                    // bf16 32768x3072
static constexpr size_t OFF_XBF   = 201326592;            // bf16 32768x1024
static constexpr size_t OFF_WBF   = OFF_XBF + 67108864;   // bf16 3072x1024
static constexpr size_t OFF_UZR   = OFF_WBF + 6291456;    // bf16 2048x1024
static constexpr size_t OFF_UH    = OFF_UZR + 4194304;    // bf16 1024x1024
// H32/R32 reuse the Xbf region (dead after the GEMM): 2 x [2][32][1024] f32
static constexpr size_t OFF_H32   = OFF_XBF;              // 262144 B
static constexpr size_t OFF_R32   = OFF_XBF + 262144;     // 262144 B

__device__ __forceinline__ float b2f(ushort_t u) {
  union { float f; unsigned i; } v;
  v.i = ((unsigned)u) << 16;
  return v.f;
}
__device__ __forceinline__ ushort_t f2b(float f) {  // round-to-nearest-even
  union { float f; unsigned i; } v;
  v.f = f;
  unsigned r = v.i + 0x7fffu + ((v.i >> 16) & 1u);
  return (ushort_t)(r >> 16);
}
// pack two fp32 bit patterns to 2 bf16 (RNE) in one u32
__device__ __forceinline__ unsigned pk2(unsigned a, unsigned b) {
  unsigned ra = (a + 0x7fffu + ((a >> 16) & 1u)) >> 16;
  unsigned rb = (b + 0x7fffu + ((b >> 16) & 1u)) & 0xffff0000u;
  return ra | rb;
}

// --- coherence-point (IF) accessors: bypass L1/L2, no fences needed --------
__device__ __forceinline__ void st_u32_sc(void* p, unsigned v) {
  asm volatile("global_store_dword %0, %1, off sc0 sc1" ::"v"(p), "v"(v)
               : "memory");
}
__device__ __forceinline__ u32x4 ld_u32x4_sc(const void* p) {  // NO waitcnt
  u32x4 r;
  asm volatile("global_load_dwordx4 %0, %1, off sc0 sc1" : "=v"(r) : "v"(p));
  return r;
}
__device__ __forceinline__ void vm_drain() {
  asm volatile("s_waitcnt vmcnt(0)" ::: "memory");
}

// ------------------------------- converts ----------------------------------
__global__ void cvt_f32_bf16x4(const float4* __restrict__ src,
                               uint2* __restrict__ dst, int n4) {
  int i = blockIdx.x * blockDim.x + threadIdx.x;
  int st = gridDim.x * blockDim.x;
  for (; i < n4; i += st) {
    float4 v = src[i];
    unsigned a = (unsigned)f2b(v.x) | ((unsigned)f2b(v.y) << 16);
    unsigned b = (unsigned)f2b(v.z) | ((unsigned)f2b(v.w) << 16);
    dst[i] = make_uint2(a, b);
  }
}

// invalidate tag buffers: write tag=1 denormal everywhere (first expected
// generation of every buffer has tag 0 -> consumers wait for real writes).
__global__ void clear_tags(unsigned* __restrict__ p, int n) {
  int i = blockIdx.x * blockDim.x + threadIdx.x;
  int st = gridDim.x * blockDim.x;
  for (; i < n; i += st) p[i] = 1u;
}

// ------------------------------- GEMM --------------------------------------
__global__ __launch_bounds__(256) void gemm_xw(
    const ushort_t* __restrict__ A, const ushort_t* __restrict__ Bm,
    const float* __restrict__ bzr, const float* __restrict__ bh,
    ushort_t* __restrict__ C) {
  __shared__ ushort_t As[128][40];
  __shared__ ushort_t Bs[128][40];
  const int bi = blockIdx.x;
  const int p = bi / 192;
  const int q = bi % 192;
  const int i0 = (p * 8 + (q & 7)) * 128;
  const int n0 = (q >> 3) * 128;
  const int tid = threadIdx.x;
  const int w = tid >> 6, l = tid & 63;
  const int wr = w >> 1, wc = w & 1;
  const int quad = l >> 4, lr = l & 15;

  f32x4 acc[4][4] = {};
  for (int kc = 0; kc < 1024; kc += 32) {
    __syncthreads();
#pragma unroll
    for (int j = 0; j < 2; ++j) {
      int c = j * 256 + tid;
      int r = c >> 2, pp = c & 3;
      *(int4*)(&As[r][pp * 8]) =
          *(const int4*)(A + (size_t)(i0 + r) * 1024 + kc + pp * 8);
      *(int4*)(&Bs[r][pp * 8]) =
          *(const int4*)(Bm + (size_t)(n0 + r) * 1024 + kc + pp * 8);
    }
    __syncthreads();
    bf16x8 af[4], bfr[4];
#pragma unroll
    for (int mb = 0; mb < 4; ++mb)
      af[mb] = *(const bf16x8*)(&As[wr * 64 + mb * 16 + lr][quad * 8]);
#pragma unroll
    for (int nb = 0; nb < 4; ++nb)
      bfr[nb] = *(const bf16x8*)(&Bs[wc * 64 + nb * 16 + lr][quad * 8]);
#pragma unroll
    for (int mb = 0; mb < 4; ++mb)
#pragma unroll
      for (int nb = 0; nb < 4; ++nb)
        acc[mb][nb] = __builtin_amdgcn_mfma_f32_16x16x32_bf16(
            af[mb], bfr[nb], acc[mb][nb], 0, 0, 0);
  }
#pragma unroll
  for (int nb = 0; nb < 4; ++nb) {
    int col = n0 + wc * 64 + nb * 16 + lr;
    float bias = (col < 2048) ? bzr[col] : bh[col - 2048];
#pragma unroll
    for (int mb = 0; mb < 4; ++mb) {
#pragma unroll
      for (int reg = 0; reg < 4; ++reg) {
        int row = i0 + wr * 64 + mb * 16 + quad * 4 + reg;
        C[(size_t)row * NC_ + col] = f2b(acc[mb][nb][reg] + bias);
      }
    }
  }
}

// ------------------------------- scan --------------------------------------
// stage 16 rows x 1024 fp32 (tagged) -> StageL as bf16. Re-loads stale chunks.
__device__ __forceinline__ void stage16(const float* __restrict__ srcb,
                                        unsigned exp, int tid,
                                        ushort_t (*St)[1032]) {
  const float* src = srcb + (size_t)tid * 4;
  u32x4 v[16];
#pragma unroll
  for (int j = 0; j < 16; ++j) v[j] = ld_u32x4_sc(src + (size_t)j * DIM_);
  __syncthreads();  // all waves done reading previous StageL contents
  vm_drain();
  unsigned stale = 0;
#pragma unroll
  for (int j = 0; j < 16; ++j) {
    unsigned bad =
        ((v[j].x ^ exp) | (v[j].y ^ exp) | (v[j].z ^ exp) | (v[j].w ^ exp)) &
        1u;
    if (bad) {
      stale |= (1u << j);
    } else {
      *(uint2*)&St[j][tid * 4] =
          make_uint2(pk2(v[j].x, v[j].y), pk2(v[j].z, v[j].w));
    }
  }
  while (stale) {
    __builtin_amdgcn_s_sleep(1);
#pragma unroll
    for (int j = 0; j < 16; ++j)
      if (stale & (1u << j)) v[j] = ld_u32x4_sc(src + (size_t)j * DIM_);
    vm_drain();
#pragma unroll
    for (int j = 0; j < 16; ++j) {
      if (stale & (1u << j)) {
        unsigned bad = ((v[j].x ^ exp) | (v[j].y ^ exp) | (v[j].z ^ exp) |
                        (v[j].w ^ exp)) &
                       1u;
        if (!bad) {
          *(uint2*)&St[j][tid * 4] =
              make_uint2(pk2(v[j].x, v[j].y), pk2(v[j].z, v[j].w));
          stale &= ~(1u << j);
        }
      }
    }
  }
  __syncthreads();  // StageL fully populated
}

__global__ __launch_bounds__(256, 1) void gru_scan(
    const ushort_t* __restrict__ P, const ushort_t* __restrict__ Uzr,
    const ushort_t* __restrict__ Uh, const float* __restrict__ h0,
    float* __restrict__ H32, float* __restrict__ R32,
    float* __restrict__ out) {
  const int g = blockIdx.x;
  const int G = g >> 5, gg = g & 31;
  const int rb0 = G * 16;   // batch base
  const int cs = gg * 32;   // column slice base
  const int tid = threadIdx.x;
  const int w = tid >> 6, l = tid & 63;
  const int quad = l >> 4, lr = l & 15;

  __shared__ ushort_t StageL[16][1032];  // stride 2064B: 16B-aligned
  __shared__ float Hl[16][33];           // fp32 master h slice
  __shared__ f32x4 red[2][64];           // phase-B k-split partials

  const int ctA = w >> 1, cbA = w & 1;
  const int khB = w >> 1, cbB = w & 1;
  const int eA = cs + cbA * 16 + lr;
  const int eB = cs + cbB * 16 + lr;

  // ---- preload weights into VGPRs ----
  bf16x8 wa[32];
  {
    const ushort_t* urow = Uzr + (size_t)(ctA * 1024 + eA) * DIM_;
#pragma unroll
    for (int it = 0; it < 32; ++it)
      wa[it] = *(const bf16x8*)(urow + it * 32 + quad * 8);
  }
  bf16x8 wb[16];
  {
    const ushort_t* urow = Uh + (size_t)eB * DIM_ + khB * 512;
#pragma unroll
    for (int it = 0; it < 16; ++it)
      wb[it] = *(const bf16x8*)(urow + it * 32 + quad * 8);
  }

  // ---- init h slice: fp32 LDS master + tagged fp32 (gen 0 -> tag 0, buf 0)
  {
    int rr = tid >> 4, cp = tid & 15;
    int c0 = cp * 2;
    float v0 = h0[(rb0 + rr) * DIM_ + cs + c0];
    float v1 = h0[(rb0 + rr) * DIM_ + cs + c0 + 1];
    Hl[rr][c0] = v0;
    Hl[rr][c0 + 1] = v1;
    st_u32_sc(&H32[(size_t)(rb0 + rr) * DIM_ + cs + c0],
              __float_as_uint(v0) & ~1u);
    st_u32_sc(&H32[(size_t)(rb0 + rr) * DIM_ + cs + c0 + 1],
              __float_as_uint(v1) & ~1u);
  }

  // prefetch P for t=0 (plain cached loads; overlap with first tag-poll)
  float pA[4], pB[4];
  {
    const size_t prow = (size_t)rb0 * NC_;
#pragma unroll
    for (int reg = 0; reg < 4; ++reg) {
      int br = quad * 4 + reg;
      pA[reg] = b2f(P[prow + (size_t)br * NC_ + ctA * 1024 + eA]);
      pB[reg] = b2f(P[prow + (size_t)br * NC_ + 2048 + eB]);
    }
  }

  for (int t = 0; t < T_; ++t) {
    const size_t bufc = (size_t)(t & 1) * 32768;        // consume H[t], RH[t]
    const unsigned tagc = (unsigned)((t >> 1) & 1);
    const size_t bufn = (size_t)((t + 1) & 1) * 32768;  // produce H[t+1]
    const unsigned tagn = (unsigned)(((t + 1) >> 1) & 1);

    // ---------------- stage h(t) into LDS (tag-polled) ----------------
    stage16(H32 + bufc + (size_t)rb0 * DIM_, tagc, tid, StageL);

    // ---------------- phase A: z and r ----------------
    f32x4 acc = {0.f, 0.f, 0.f, 0.f};
#pragma unroll
    for (int it = 0; it < 32; ++it) {
      bf16x8 a = *(const bf16x8*)&StageL[lr][it * 32 + quad * 8];
      acc = __builtin_amdgcn_mfma_f32_16x16x32_bf16(a, wa[it], acc, 0, 0, 0);
    }
    float zv[4];
#pragma unroll
    for (int reg = 0; reg < 4; ++reg) {
      int br = quad * 4 + reg;
      float pre = acc[reg] + pA[reg];
      float sv = 1.f / (1.f + __expf(-pre));
      if (ctA == 0) {
        zv[reg] = sv;  // z stays in registers (same lane map in phase B)
      } else {
        float hv = Hl[br][cbA * 16 + lr];
        unsigned u = (__float_as_uint(sv * hv) & ~1u) | tagc;
        st_u32_sc(&R32[bufc + (size_t)(rb0 + br) * DIM_ + eA], u);
      }
    }

    // ---------------- stage r*h(t) into LDS (tag-polled) ----------------
    stage16(R32 + bufc + (size_t)rb0 * DIM_, tagc, tid, StageL);

    // ---------------- phase B: h~ and update ----------------
    f32x4 acch = {0.f, 0.f, 0.f, 0.f};
#pragma unroll
    for (int it = 0; it < 16; ++it) {
      bf16x8 a = *(const bf16x8*)&StageL[lr][khB * 512 + it * 32 + quad * 8];
      acch = __builtin_amdgcn_mfma_f32_16x16x32_bf16(a, wb[it], acch, 0, 0, 0);
    }
    if (w >= 2) red[cbB][l] = acch;
    __syncthreads();
    if (w < 2) {
      f32x4 oth4 = red[cbB][l];
#pragma unroll
      for (int reg = 0; reg < 4; ++reg) {
        int br = quad * 4 + reg;
        float ax = pB[reg] + acch[reg] + oth4[reg];
        float e = __expf(2.f * fabsf(ax));
        float th = copysignf(1.f - 2.f / (e + 1.f), ax);
        float hv = Hl[br][cbB * 16 + lr];
        float z = zv[reg];
        float hn = (1.f - z) * hv + z * th;
        Hl[br][cbB * 16 + lr] = hn;
        int gb = rb0 + br;
        unsigned u = (__float_as_uint(hn) & ~1u) | tagn;
        st_u32_sc(&H32[bufn + (size_t)gb * DIM_ + eB], u);
        out[((size_t)t * BATCH_ + gb) * DIM_ + eB] = hn;
      }
    }

    // prefetch P for t+1 (completes during next tag-poll)
    {
      int tn = (t + 1 < T_) ? t + 1 : t;
      const size_t prow = ((size_t)(tn * BATCH_ + rb0)) * NC_;
#pragma unroll
      for (int reg = 0; reg < 4; ++reg) {
        int br = quad * 4 + reg;
        pA[reg] = b2f(P[prow + (size_t)br * NC_ + ctA * 1024 + eA]);
        pB[reg] = b2f(P[prow + (size_t)br * NC_ + 2048 + eB]);
      }
    }
  }
}

// ------------------------------- launch ------------------------------------
extern "C" void kernel_launch(void* const* d_in, const int* in_sizes, int n_in,
                              void* d_out, int out_size, void* d_ws,
                              size_t ws_size, hipStream_t stream) {
  const float* x   = (const float*)d_in[0];
  const float* h0  = (const float*)d_in[1];
  const float* Wzr = (const float*)d_in[2];
  const float* Uzr = (const float*)d_in[3];
  const float* Wh  = (const float*)d_in[4];
  const float* Uh  = (const float*)d_in[5];
  const float* bzr = (const float*)d_in[6];
  const float* bh  = (const float*)d_in[7];
  char* ws = (char*)d_ws;
  ushort_t* P    = (ushort_t*)(ws + OFF_P);
  ushort_t* Xbf  = (ushort_t*)(ws + OFF_XBF);
  ushort_t* Wbf  = (ushort_t*)(ws + OFF_WBF);
  ushort_t* Uzrb = (ushort_t*)(ws + OFF_UZR);
  ushort_t* Uhb  = (ushort_t*)(ws + OFF_UH);
  float* H32 = (float*)(ws + OFF_H32);
  float* R32 = (float*)(ws + OFF_R32);
  float* out = (float*)d_out;

  cvt_f32_bf16x4<<<1024, 256, 0, stream>>>((const float4*)x, (uint2*)Xbf,
                                           33554432 / 4);
  cvt_f32_bf16x4<<<256, 256, 0, stream>>>((const float4*)Wzr, (uint2*)Wbf,
                                          2097152 / 4);
  cvt_f32_bf16x4<<<128, 256, 0, stream>>>((const float4*)Wh,
                                          (uint2*)(Wbf + 2097152), 1048576 / 4);
  cvt_f32_bf16x4<<<256, 256, 0, stream>>>((const float4*)Uzr, (uint2*)Uzrb,
                                          2097152 / 4);
  cvt_f32_bf16x4<<<128, 256, 0, stream>>>((const float4*)Uh, (uint2*)Uhb,
                                          1048576 / 4);
  gemm_xw<<<6144, 256, 0, stream>>>(Xbf, Wbf, bzr, bh, P);
  // invalidate tag buffers AFTER gemm (they alias the Xbf region)
  clear_tags<<<256, 256, 0, stream>>>((unsigned*)(ws + OFF_H32),
                                      (262144 * 2) / 4);
  gru_scan<<<64, 256, 0, stream>>>(P, Uzrb, Uhb, h0, H32, R32, out);
}

// Round 4
// 7873.232 us; speedup vs baseline: 1.2473x; 1.2473x over previous
//
#include <hip/hip_runtime.h>

// ---------------------------------------------------------------------------
// GRU scan on MI355X. Phase 1: bf16 GEMM P = X W^T + b. Phase 2: persistent
// scan, 2 groups x 32 wgs, U weights in VGPRs.
// R6 change: handshake traffic at AGENT scope (sc1) instead of SYSTEM scope
// (sc0 sc1). gfx940+ {sc1,sc0} is a scope encoding; sc0-alone (R5) was too
// narrow (flags never visible -> abort), sc0+sc1 (R2) was too wide (system
// scope forces HBM round trips: R2 FETCH_SIZE showed ~250KB/phase of payload
// going to HBM). Agent scope = coherence at the MALL (256MB Infinity Cache):
// every serial round trip in the per-phase chain (payload drain, flag
// store/poll, 32KB payload stage) terminates at the MALL, not HBM.
// Budgeted barrier polls kept from R5: on visibility failure we abort cleanly
// (fast wrong answer + counters) instead of hanging the container.
// ---------------------------------------------------------------------------

typedef __attribute__((ext_vector_type(8))) __bf16 bf16x8;
typedef __attribute__((ext_vector_type(4))) float f32x4;
typedef unsigned short ushort_t;
typedef unsigned long long u64;

#define DIM_ 1024
#define BATCH_ 32
#define T_ 1024
#define NC_ 3072  // 3*DIM

// workspace layout (bytes)
static constexpr size_t OFF_P     = 0;                    // bf16 32768x3072
static constexpr size_t OFF_XBF   = 201326592;            // bf16 32768x1024
static constexpr size_t OFF_WBF   = OFF_XBF + 67108864;   // bf16 3072x1024
static constexpr size_t OFF_UZR   = OFF_WBF + 6291456;    // bf16 2048x1024
static constexpr size_t OFF_UH    = OFF_UZR + 4194304;    // bf16 1024x1024
static constexpr size_t OFF_HB    = OFF_UH  + 2097152;    // bf16 32x1024
static constexpr size_t OFF_RH    = OFF_HB  + 65536;      // bf16 32x1024
static constexpr size_t OFF_FLAGS = OFF_RH  + 65536;      // 256 B

__device__ __forceinline__ float b2f(ushort_t u) {
  union { float f; unsigned i; } v;
  v.i = ((unsigned)u) << 16;
  return v.f;
}
__device__ __forceinline__ ushort_t f2b(float f) {  // round-to-nearest-even
  union { float f; unsigned i; } v;
  v.f = f;
  unsigned r = v.i + 0x7fffu + ((v.i >> 16) & 1u);
  return (ushort_t)(r >> 16);
}

// --- agent-scope (MALL coherence point) accessors --------------------------
__device__ __forceinline__ void st_u32_sc(void* p, unsigned v) {
  asm volatile("global_store_dword %0, %1, off sc1" ::"v"(p), "v"(v)
               : "memory");
}
__device__ __forceinline__ unsigned ld_u32_sc(const void* p) {
  unsigned r;
  asm volatile("global_load_dword %0, %1, off sc1\n\ts_waitcnt vmcnt(0)"
               : "=v"(r) : "v"(p) : "memory");
  return r;
}
__device__ __forceinline__ u64 ld_u64_sc(const void* p) {  // NO waitcnt!
  u64 r;
  asm volatile("global_load_dwordx2 %0, %1, off sc1" : "=v"(r) : "v"(p));
  return r;
}
__device__ __forceinline__ void vm_drain() {
  asm volatile("s_waitcnt vmcnt(0)" ::: "memory");
}

// ------------------------------- converts ----------------------------------
__global__ void cvt_f32_bf16x4(const float4* __restrict__ src,
                               uint2* __restrict__ dst, int n4) {
  int i = blockIdx.x * blockDim.x + threadIdx.x;
  int st = gridDim.x * blockDim.x;
  for (; i < n4; i += st) {
    float4 v = src[i];
    unsigned a = (unsigned)f2b(v.x) | ((unsigned)f2b(v.y) << 16);
    unsigned b = (unsigned)f2b(v.z) | ((unsigned)f2b(v.w) << 16);
    dst[i] = make_uint2(a, b);
  }
}

// agent-scope stores so no stale MALL copy can alias the flags
__global__ void zero_flags(unsigned* f) { st_u32_sc(f + threadIdx.x, 0u); }

// ------------------------------- GEMM --------------------------------------
__global__ __launch_bounds__(256) void gemm_xw(
    const ushort_t* __restrict__ A, const ushort_t* __restrict__ Bm,
    const float* __restrict__ bzr, const float* __restrict__ bh,
    ushort_t* __restrict__ C) {
  __shared__ ushort_t As[128][40];
  __shared__ ushort_t Bs[128][40];
  const int bi = blockIdx.x;
  const int p = bi / 192;
  const int q = bi % 192;
  const int i0 = (p * 8 + (q & 7)) * 128;
  const int n0 = (q >> 3) * 128;
  const int tid = threadIdx.x;
  const int w = tid >> 6, l = tid & 63;
  const int wr = w >> 1, wc = w & 1;
  const int quad = l >> 4, lr = l & 15;

  f32x4 acc[4][4] = {};
  for (int kc = 0; kc < 1024; kc += 32) {
    __syncthreads();
#pragma unroll
    for (int j = 0; j < 2; ++j) {
      int c = j * 256 + tid;
      int r = c >> 2, pp = c & 3;
      *(int4*)(&As[r][pp * 8]) =
          *(const int4*)(A + (size_t)(i0 + r) * 1024 + kc + pp * 8);
      *(int4*)(&Bs[r][pp * 8]) =
          *(const int4*)(Bm + (size_t)(n0 + r) * 1024 + kc + pp * 8);
    }
    __syncthreads();
    bf16x8 af[4], bfr[4];
#pragma unroll
    for (int mb = 0; mb < 4; ++mb)
      af[mb] = *(const bf16x8*)(&As[wr * 64 + mb * 16 + lr][quad * 8]);
#pragma unroll
    for (int nb = 0; nb < 4; ++nb)
      bfr[nb] = *(const bf16x8*)(&Bs[wc * 64 + nb * 16 + lr][quad * 8]);
#pragma unroll
    for (int mb = 0; mb < 4; ++mb)
#pragma unroll
      for (int nb = 0; nb < 4; ++nb)
        acc[mb][nb] = __builtin_amdgcn_mfma_f32_16x16x32_bf16(
            af[mb], bfr[nb], acc[mb][nb], 0, 0, 0);
  }
#pragma unroll
  for (int nb = 0; nb < 4; ++nb) {
    int col = n0 + wc * 64 + nb * 16 + lr;
    float bias = (col < 2048) ? bzr[col] : bh[col - 2048];
#pragma unroll
    for (int mb = 0; mb < 4; ++mb) {
#pragma unroll
      for (int reg = 0; reg < 4; ++reg) {
        int row = i0 + wr * 64 + mb * 16 + quad * 4 + reg;
        C[(size_t)row * NC_ + col] = f2b(acc[mb][nb][reg] + bias);
      }
    }
  }
}

// ------------------------------- scan --------------------------------------
// barrier: per-wave vmcnt drain -> syncthreads -> flag store (sc1, MALL) ->
// 32-lane BUDGETED poll (sc1, MALL) -> syncthreads. Returns true on abort.
__device__ __forceinline__ bool group_barrier(unsigned* gflags, int gg,
                                              unsigned gen, int tid,
                                              int* s_abort) {
  vm_drain();       // this wave's payload stores are at the MALL
  __syncthreads();  // all waves of wg drained
  if (tid == 0) st_u32_sc(gflags + gg, gen);
  if (tid < 32) {
    int budget = 1 << 21;  // ~0.5s worst case; then clean abort (no hang)
    while (ld_u32_sc(gflags + tid) < gen) {
      __builtin_amdgcn_s_sleep(1);
      if (--budget == 0) { *s_abort = 1; break; }
    }
  }
  __syncthreads();
  return *s_abort != 0;
}

__global__ __launch_bounds__(256, 1) void gru_scan(
    const ushort_t* __restrict__ P, const ushort_t* __restrict__ Uzr,
    const ushort_t* __restrict__ Uh, const float* __restrict__ h0,
    ushort_t* __restrict__ Hb, ushort_t* __restrict__ RH,
    unsigned* __restrict__ flags, float* __restrict__ out) {
  const int g = blockIdx.x;
  const int G = g >> 5, gg = g & 31;
  const int rb0 = G * 16;   // batch base
  const int cs = gg * 32;   // column slice base
  const int tid = threadIdx.x;
  const int w = tid >> 6, l = tid & 63;
  const int quad = l >> 4, lr = l & 15;
  unsigned* gflags = flags + G * 32;

  __shared__ int s_abort;
  if (tid == 0) s_abort = 0;

  // staged payload (full 16x1024 of Hb in phase A / RH in phase B)
  __shared__ ushort_t StageL[16][1032];  // stride 2064B: 16B-aligned, 2-way bk
  __shared__ float Hl[16][33];           // fp32 master h slice
  __shared__ f32x4 red[2][64];           // phase-B k-split partials

  const int ctA = w >> 1, cbA = w & 1;
  const int khB = w >> 1, cbB = w & 1;
  const int eA = cs + cbA * 16 + lr;
  const int eB = cs + cbB * 16 + lr;

  // ---- preload weights into VGPRs ----
  bf16x8 wa[32];
  {
    const ushort_t* urow = Uzr + (size_t)(ctA * 1024 + eA) * DIM_;
#pragma unroll
    for (int it = 0; it < 32; ++it)
      wa[it] = *(const bf16x8*)(urow + it * 32 + quad * 8);
  }
  bf16x8 wb[16];
  {
    const ushort_t* urow = Uh + (size_t)eB * DIM_ + khB * 512;
#pragma unroll
    for (int it = 0; it < 16; ++it)
      wb[it] = *(const bf16x8*)(urow + it * 32 + quad * 8);
  }

  // ---- init h slice: fp32 LDS master + packed sc1 global ----
  {
    int rr = tid >> 4, cp = tid & 15;
    int c0 = cp * 2;
    float v0 = h0[(rb0 + rr) * DIM_ + cs + c0];
    float v1 = h0[(rb0 + rr) * DIM_ + cs + c0 + 1];
    Hl[rr][c0] = v0;
    Hl[rr][c0 + 1] = v1;
    unsigned pk = (unsigned)f2b(v0) | ((unsigned)f2b(v1) << 16);
    st_u32_sc(&Hb[(size_t)(rb0 + rr) * DIM_ + cs + c0], pk);
  }

  // prefetch P for t=0 (plain cached loads; overlap with init barrier)
  float pA[4], pB[4];
  {
    const size_t prow = (size_t)rb0 * NC_;
#pragma unroll
    for (int reg = 0; reg < 4; ++reg) {
      int br = quad * 4 + reg;
      pA[reg] = b2f(P[prow + (size_t)br * NC_ + ctA * 1024 + eA]);
      pB[reg] = b2f(P[prow + (size_t)br * NC_ + 2048 + eB]);
    }
  }

  unsigned gen = 1;
  if (group_barrier(gflags, gg, gen, tid, &s_abort)) return;

  for (int t = 0; t < T_; ++t) {
    // ---------------- stage Hb (16x1024 bf16) into LDS ----------------
    {
      u64 tmp[16];
#pragma unroll
      for (int j = 0; j < 16; ++j)
        tmp[j] =
            ld_u64_sc((const u64*)(Hb + (size_t)(rb0 + j) * DIM_) + tid);
      vm_drain();
#pragma unroll
      for (int j = 0; j < 16; ++j) *(u64*)&StageL[j][tid * 4] = tmp[j];
    }
    __syncthreads();

    // ---------------- phase A: z and r ----------------
    f32x4 acc = {0.f, 0.f, 0.f, 0.f};
#pragma unroll
    for (int it = 0; it < 32; ++it) {
      bf16x8 a = *(const bf16x8*)&StageL[lr][it * 32 + quad * 8];
      acc = __builtin_amdgcn_mfma_f32_16x16x32_bf16(a, wa[it], acc, 0, 0, 0);
    }
    float zv[4];
#pragma unroll
    for (int reg = 0; reg < 4; ++reg) {
      int br = quad * 4 + reg;
      float pre = acc[reg] + pA[reg];
      float sv = 1.f / (1.f + __expf(-pre));
      if (ctA == 0) {
        zv[reg] = sv;  // z stays in registers (same lane map in phase B)
      } else {
        float hv = Hl[br][cbA * 16 + lr];
        unsigned own = f2b(sv * hv);
        unsigned oth = (unsigned)__shfl_xor((int)own, 1);
        if ((l & 1) == 0) {
          unsigned pk = own | (oth << 16);
          st_u32_sc(&RH[(size_t)(rb0 + br) * DIM_ + eA], pk);
        }
      }
    }
    ++gen;
    if (group_barrier(gflags, gg, gen, tid, &s_abort)) return;

    // ---------------- stage RH (16x1024 bf16) into LDS ----------------
    {
      u64 tmp[16];
#pragma unroll
      for (int j = 0; j < 16; ++j)
        tmp[j] =
            ld_u64_sc((const u64*)(RH + (size_t)(rb0 + j) * DIM_) + tid);
      vm_drain();
#pragma unroll
      for (int j = 0; j < 16; ++j) *(u64*)&StageL[j][tid * 4] = tmp[j];
    }
    __syncthreads();

    // ---------------- phase B: h~ and update ----------------
    f32x4 acch = {0.f, 0.f, 0.f, 0.f};
#pragma unroll
    for (int it = 0; it < 16; ++it) {
      bf16x8 a = *(const bf16x8*)&StageL[lr][khB * 512 + it * 32 + quad * 8];
      acch = __builtin_amdgcn_mfma_f32_16x16x32_bf16(a, wb[it], acch, 0, 0, 0);
    }
    if (w >= 2) red[cbB][l] = acch;
    __syncthreads();
    if (w < 2) {
      f32x4 oth4 = red[cbB][l];
#pragma unroll
      for (int reg = 0; reg < 4; ++reg) {
        int br = quad * 4 + reg;
        float ax = pB[reg] + acch[reg] + oth4[reg];
        float e = __expf(2.f * fabsf(ax));
        float th = copysignf(1.f - 2.f / (e + 1.f), ax);
        float hv = Hl[br][cbB * 16 + lr];
        float z = zv[reg];
        float hn = (1.f - z) * hv + z * th;
        Hl[br][cbB * 16 + lr] = hn;
        int gb = rb0 + br;
        // packed sc1 h store for other wgs (agent scope, MALL-resident)
        unsigned own = f2b(hn);
        unsigned otherh = (unsigned)__shfl_xor((int)own, 1);
        float hn_oth = __shfl_xor(hn, 1);
        if ((l & 1) == 0) {
          st_u32_sc(&Hb[(size_t)gb * DIM_ + eB], own | (otherh << 16));
          *(float2*)&out[((size_t)t * BATCH_ + gb) * DIM_ + eB] =
              make_float2(hn, hn_oth);
        }
      }
    }

    // prefetch P for t+1 (completes during the barrier's vmcnt drain)
    {
      int tn = (t + 1 < T_) ? t + 1 : t;
      const size_t prow = ((size_t)(tn * BATCH_ + rb0)) * NC_;
#pragma unroll
      for (int reg = 0; reg < 4; ++reg) {
        int br = quad * 4 + reg;
        pA[reg] = b2f(P[prow + (size_t)br * NC_ + ctA * 1024 + eA]);
        pB[reg] = b2f(P[prow + (size_t)br * NC_ + 2048 + eB]);
      }
    }
    ++gen;
    if (group_barrier(gflags, gg, gen, tid, &s_abort)) return;
  }
}

// ------------------------------- launch ------------------------------------
extern "C" void kernel_launch(void* const* d_in, const int* in_sizes, int n_in,
                              void* d_out, int out_size, void* d_ws,
                              size_t ws_size, hipStream_t stream) {
  const float* x   = (const float*)d_in[0];
  const float* h0  = (const float*)d_in[1];
  const float* Wzr = (const float*)d_in[2];
  const float* Uzr = (const float*)d_in[3];
  const float* Wh  = (const float*)d_in[4];
  const float* Uh  = (const float*)d_in[5];
  const float* bzr = (const float*)d_in[6];
  const float* bh  = (const float*)d_in[7];
  char* ws = (char*)d_ws;
  ushort_t* P     = (ushort_t*)(ws + OFF_P);
  ushort_t* Xbf   = (ushort_t*)(ws + OFF_XBF);
  ushort_t* Wbf   = (ushort_t*)(ws + OFF_WBF);
  ushort_t* Uzrb  = (ushort_t*)(ws + OFF_UZR);
  ushort_t* Uhb   = (ushort_t*)(ws + OFF_UH);
  ushort_t* Hb    = (ushort_t*)(ws + OFF_HB);
  ushort_t* RH    = (ushort_t*)(ws + OFF_RH);
  unsigned* flags = (unsigned*)(ws + OFF_FLAGS);
  float* out = (float*)d_out;

  zero_flags<<<1, 64, 0, stream>>>(flags);
  cvt_f32_bf16x4<<<1024, 256, 0, stream>>>((const float4*)x, (uint2*)Xbf,
                                           33554432 / 4);
  cvt_f32_bf16x4<<<256, 256, 0, stream>>>((const float4*)Wzr, (uint2*)Wbf,
                                          2097152 / 4);
  cvt_f32_bf16x4<<<128, 256, 0, stream>>>((const float4*)Wh,
                                          (uint2*)(Wbf + 2097152), 1048576 / 4);
  cvt_f32_bf16x4<<<256, 256, 0, stream>>>((const float4*)Uzr, (uint2*)Uzrb,
                                          2097152 / 4);
  cvt_f32_bf16x4<<<128, 256, 0, stream>>>((const float4*)Uh, (uint2*)Uhb,
                                          1048576 / 4);
  gemm_xw<<<6144, 256, 0, stream>>>(Xbf, Wbf, bzr, bh, P);
  gru_scan<<<64, 256, 0, stream>>>(P, Uzrb, Uhb, h0, Hb, RH, flags, out);
}